// Round 1
// baseline (157.253 us; speedup 1.0000x reference)
//
#include <hip/hip_runtime.h>
#include <math.h>

#define H 2048
#define E 2048
#define ATTN 50
#define OUTSZ 32000

__device__ inline float wave_reduce_sum(float v) {
  #pragma unroll
  for (int off = 32; off > 0; off >>= 1) v += __shfl_down(v, off, 64);
  return v;
}

__device__ inline float sigmoidf_(float x) { return 1.f / (1.f + expf(-x)); }

// one wave (64 lanes) per attention position t: score[t] = attn_W[t,:2048]·emb + attn_W[t,2048:]·h0 + b[t]
__global__ void attn_scores_k(const int* __restrict__ idx,
                              const float* __restrict__ embed_table,
                              const float* __restrict__ h0,
                              const float* __restrict__ attn_W,
                              const float* __restrict__ attn_b,
                              float* __restrict__ scores) {
  int t = blockIdx.x;
  int lane = threadIdx.x;
  const float* emb = embed_table + (size_t)idx[0] * E;
  const float* row = attn_W + (size_t)t * (E + H);
  float acc = 0.f;
  for (int k = lane * 4; k < E; k += 256) {
    float4 w = *(const float4*)(row + k);
    float4 e = *(const float4*)(emb + k);
    acc += w.x * e.x + w.y * e.y + w.z * e.z + w.w * e.w;
    float4 w2 = *(const float4*)(row + E + k);
    float4 h = *(const float4*)(h0 + k);
    acc += w2.x * h.x + w2.y * h.y + w2.z * h.z + w2.w * h.w;
  }
  acc = wave_reduce_sum(acc);
  if (lane == 0) scores[t] = acc + attn_b[t];
}

// single wave: softmax over 50 scores (in-place), also write attn_weights output
__global__ void attn_softmax_k(float* __restrict__ scores_weights,
                               float* __restrict__ attnw_out) {
  int lane = threadIdx.x;
  float v = (lane < ATTN) ? scores_weights[lane] : -INFINITY;
  float m = v;
  #pragma unroll
  for (int off = 32; off > 0; off >>= 1) m = fmaxf(m, __shfl_down(m, off, 64));
  m = __shfl(m, 0, 64);
  float e = (lane < ATTN) ? expf(v - m) : 0.f;
  float s = wave_reduce_sum(e);
  s = __shfl(s, 0, 64);
  if (lane < ATTN) {
    float w = e / s;
    scores_weights[lane] = w;
    attnw_out[lane] = w;
  }
}

// build xcat = [emb, attn_weights @ enc]  (2048 threads, coalesced over j)
__global__ void attn_apply_k(const int* __restrict__ idx,
                             const float* __restrict__ embed_table,
                             const float* __restrict__ weights,
                             const float* __restrict__ enc,
                             float* __restrict__ xcat) {
  int j = blockIdx.x * blockDim.x + threadIdx.x;  // 0..2047
  const float* emb = embed_table + (size_t)idx[0] * E;
  float a = 0.f;
  #pragma unroll 10
  for (int t = 0; t < ATTN; t++) a += weights[t] * enc[t * H + j];
  xcat[j] = emb[j];
  xcat[E + j] = a;
}

// generic wave-per-row matvec: y = W @ x + b, row length K (multiple of 256)
template <int K>
__global__ void matvec_k(const float* __restrict__ W, const float* __restrict__ x,
                         const float* __restrict__ b, float* __restrict__ y, int rows) {
  int w = (int)((blockIdx.x * (unsigned)blockDim.x + threadIdx.x) >> 6);
  int lane = threadIdx.x & 63;
  if (w >= rows) return;
  const float* row = W + (size_t)w * K;
  float acc = 0.f;
  #pragma unroll
  for (int k = lane * 4; k < K; k += 256) {
    float4 w4 = *(const float4*)(row + k);
    float4 x4 = *(const float4*)(x + k);
    acc += w4.x * x4.x + w4.y * x4.y + w4.z * x4.z + w4.w * x4.w;
  }
  acc = wave_reduce_sum(acc);
  if (lane == 0) y[w] = acc + b[w];
}

// fused LSTM step: wave j computes all 4 gates (rows j, j+H, j+2H, j+3H of Wih & Whh),
// applies activations, writes h/c to d_out and h to xnext.
__global__ void lstm_k(const float* __restrict__ Wih, const float* __restrict__ Whh,
                       const float* __restrict__ bih, const float* __restrict__ bhh,
                       const float* __restrict__ x, const float* __restrict__ hin,
                       const float* __restrict__ cin,
                       float* __restrict__ hout, float* __restrict__ cout,
                       float* __restrict__ xnext) {
  int j = (int)((blockIdx.x * (unsigned)blockDim.x + threadIdx.x) >> 6);
  int lane = threadIdx.x & 63;
  float acc[4];
  #pragma unroll
  for (int g = 0; g < 4; g++) {
    const float* wi = Wih + (size_t)(g * H + j) * H;
    const float* wh = Whh + (size_t)(g * H + j) * H;
    float a = 0.f;
    #pragma unroll
    for (int k = lane * 4; k < H; k += 256) {
      float4 wi4 = *(const float4*)(wi + k);
      float4 x4 = *(const float4*)(x + k);
      a += wi4.x * x4.x + wi4.y * x4.y + wi4.z * x4.z + wi4.w * x4.w;
      float4 wh4 = *(const float4*)(wh + k);
      float4 h4 = *(const float4*)(hin + k);
      a += wh4.x * h4.x + wh4.y * h4.y + wh4.z * h4.z + wh4.w * h4.w;
    }
    acc[g] = a;
  }
  #pragma unroll
  for (int g = 0; g < 4; g++) acc[g] = wave_reduce_sum(acc[g]);
  if (lane == 0) {
    float ig = sigmoidf_(acc[0] + bih[j] + bhh[j]);
    float fg = sigmoidf_(acc[1] + bih[H + j] + bhh[H + j]);
    float gg = tanhf(acc[2] + bih[2 * H + j] + bhh[2 * H + j]);
    float og = sigmoidf_(acc[3] + bih[3 * H + j] + bhh[3 * H + j]);
    float c = fg * cin[j] + ig * gg;
    float h = og * tanhf(c);
    hout[j] = h;
    cout[j] = c;
    xnext[j] = h;
  }
}

// single block: max and log-sum-exp over 32000 logits -> scal[0]=max, scal[1]=log(sum)
__global__ void lse_k(const float* __restrict__ logits, float* __restrict__ scal) {
  __shared__ float red[16];
  __shared__ float smax;
  int tid = threadIdx.x;
  float m = -INFINITY;
  for (int i = tid; i < OUTSZ; i += 1024) m = fmaxf(m, logits[i]);
  #pragma unroll
  for (int off = 32; off > 0; off >>= 1) m = fmaxf(m, __shfl_down(m, off, 64));
  if ((tid & 63) == 0) red[tid >> 6] = m;
  __syncthreads();
  if (tid == 0) {
    float mm = -INFINITY;
    for (int i = 0; i < 16; i++) mm = fmaxf(mm, red[i]);
    smax = mm;
  }
  __syncthreads();
  float M = smax;
  float s = 0.f;
  for (int i = tid; i < OUTSZ; i += 1024) s += expf(logits[i] - M);
  s = wave_reduce_sum(s);
  __syncthreads();
  if ((tid & 63) == 0) red[tid >> 6] = s;
  __syncthreads();
  if (tid == 0) {
    float ss = 0.f;
    for (int i = 0; i < 16; i++) ss += red[i];
    scal[0] = M;
    scal[1] = logf(ss);
  }
}

__global__ void logsoftmax_out_k(const float* __restrict__ logits,
                                 const float* __restrict__ scal,
                                 float* __restrict__ out) {
  int i = blockIdx.x * blockDim.x + threadIdx.x;
  if (i < OUTSZ) out[i] = logits[i] - scal[0] - scal[1];
}

extern "C" void kernel_launch(void* const* d_in, const int* in_sizes, int n_in,
                              void* d_out, int out_size, void* d_ws, size_t ws_size,
                              hipStream_t stream) {
  const int* idx = (const int*)d_in[0];
  const float* hidden = (const float*)d_in[1];   // [2,1,2048]
  const float* cell = (const float*)d_in[2];     // [2,1,2048]
  const float* enc = (const float*)d_in[3];      // [50,2048]
  const float* embed = (const float*)d_in[4];    // [32000,2048]
  const float* attn_W = (const float*)d_in[5];   // [50,4096]
  const float* attn_b = (const float*)d_in[6];   // [50]
  const float* comb_W = (const float*)d_in[7];   // [2048,4096]
  const float* comb_b = (const float*)d_in[8];   // [2048]
  const float* Wih = (const float*)d_in[9];      // [2,8192,2048]
  const float* Whh = (const float*)d_in[10];     // [2,8192,2048]
  const float* bih = (const float*)d_in[11];     // [2,8192]
  const float* bhh = (const float*)d_in[12];     // [2,8192]
  const float* out_W = (const float*)d_in[13];   // [32000,2048]
  const float* out_b = (const float*)d_in[14];   // [32000]
  float* out = (float*)d_out;

  // workspace layout (floats)
  float* ws = (float*)d_ws;
  float* scores = ws;            // 64 (scores, then normalized weights)
  float* scal = ws + 64;         // 2 (max, log-sum-exp)
  float* xcat = ws + 128;        // 4096
  float* x0 = ws + 128 + 4096;   // 2048  (combine output)
  float* x1 = x0 + 2048;         // 2048  (layer0 h)
  float* x2 = x1 + 2048;         // 2048  (layer1 h)
  float* logits = ws + 16384;    // 32000

  // output layout: logits(32000) | h_stack(4096) | c_stack(4096) | attn_weights(50)
  float* out_h = out + 32000;
  float* out_c = out + 36096;
  float* out_attnw = out + 40192;

  attn_scores_k<<<ATTN, 64, 0, stream>>>(idx, embed, hidden, attn_W, attn_b, scores);
  attn_softmax_k<<<1, 64, 0, stream>>>(scores, out_attnw);
  attn_apply_k<<<8, 256, 0, stream>>>(idx, embed, scores, enc, xcat);
  matvec_k<4096><<<512, 256, 0, stream>>>(comb_W, xcat, comb_b, x0, H);
  lstm_k<<<512, 256, 0, stream>>>(Wih, Whh, bih, bhh, x0, hidden, cell,
                                  out_h, out_c, x1);
  lstm_k<<<512, 256, 0, stream>>>(Wih + (size_t)4 * H * H, Whh + (size_t)4 * H * H,
                                  bih + 4 * H, bhh + 4 * H,
                                  x1, hidden + H, cell + H,
                                  out_h + H, out_c + H, x2);
  matvec_k<2048><<<8000, 256, 0, stream>>>(out_W, x2, out_b, logits, OUTSZ);
  lse_k<<<1, 1024, 0, stream>>>(logits, scal);
  logsoftmax_out_k<<<125, 256, 0, stream>>>(logits, scal, out);
}

// Round 2
// 129.899 us; speedup vs baseline: 1.2106x; 1.2106x over previous
//
#include <hip/hip_runtime.h>
#include <math.h>

#define H 2048
#define E 2048
#define ATTN 50
#define OUTSZ 32000

__device__ inline float wave_reduce_sum(float v) {
  #pragma unroll
  for (int off = 32; off > 0; off >>= 1) v += __shfl_down(v, off, 64);
  return v;
}

__device__ inline float wave_reduce_max(float v) {
  #pragma unroll
  for (int off = 32; off > 0; off >>= 1) v = fmaxf(v, __shfl_down(v, off, 64));
  return v;
}

__device__ inline float sigmoidf_(float x) { return 1.f / (1.f + expf(-x)); }

// one wave (64 lanes) per attention position t: score[t] = attn_W[t,:2048]·emb + attn_W[t,2048:]·h0 + b[t]
__global__ void attn_scores_k(const int* __restrict__ idx,
                              const float* __restrict__ embed_table,
                              const float* __restrict__ h0,
                              const float* __restrict__ attn_W,
                              const float* __restrict__ attn_b,
                              float* __restrict__ scores) {
  int t = blockIdx.x;
  int lane = threadIdx.x;
  const float* emb = embed_table + (size_t)idx[0] * E;
  const float* row = attn_W + (size_t)t * (E + H);
  float acc = 0.f;
  for (int k = lane * 4; k < E; k += 256) {
    float4 w = *(const float4*)(row + k);
    float4 e = *(const float4*)(emb + k);
    acc += w.x * e.x + w.y * e.y + w.z * e.z + w.w * e.w;
    float4 w2 = *(const float4*)(row + E + k);
    float4 h = *(const float4*)(h0 + k);
    acc += w2.x * h.x + w2.y * h.y + w2.z * h.z + w2.w * h.w;
  }
  acc = wave_reduce_sum(acc);
  if (lane == 0) scores[t] = acc + attn_b[t];
}

// fused: each block recomputes softmax over the 50 raw scores (cheap), then
// computes its slice of xcat = [emb, softmax(scores) @ enc]. Block 0 also
// writes the attn_weights output.
__global__ void attn_apply_k(const int* __restrict__ idx,
                             const float* __restrict__ embed_table,
                             const float* __restrict__ scores,
                             const float* __restrict__ enc,
                             float* __restrict__ xcat,
                             float* __restrict__ attnw_out) {
  __shared__ float w[ATTN];
  int tid = threadIdx.x;
  if (tid < 64) {
    float v = (tid < ATTN) ? scores[tid] : -INFINITY;
    float m = wave_reduce_max(v);
    m = __shfl(m, 0, 64);
    float e = (tid < ATTN) ? expf(v - m) : 0.f;
    float s = wave_reduce_sum(e);
    s = __shfl(s, 0, 64);
    if (tid < ATTN) {
      float ww = e / s;
      w[tid] = ww;
      if (blockIdx.x == 0) attnw_out[tid] = ww;
    }
  }
  __syncthreads();
  int j = blockIdx.x * 256 + tid;  // 0..2047
  const float* emb = embed_table + (size_t)idx[0] * E;
  float a = 0.f;
  #pragma unroll 10
  for (int t = 0; t < ATTN; t++) a += w[t] * enc[t * H + j];
  xcat[j] = emb[j];
  xcat[E + j] = a;
}

// generic wave-per-row matvec: y = W @ x + b, row length K (multiple of 256)
template <int K>
__global__ void matvec_k(const float* __restrict__ W, const float* __restrict__ x,
                         const float* __restrict__ b, float* __restrict__ y, int rows) {
  int w = (int)((blockIdx.x * (unsigned)blockDim.x + threadIdx.x) >> 6);
  int lane = threadIdx.x & 63;
  if (w >= rows) return;
  const float* row = W + (size_t)w * K;
  float acc = 0.f;
  #pragma unroll
  for (int k = lane * 4; k < K; k += 256) {
    float4 w4 = *(const float4*)(row + k);
    float4 x4 = *(const float4*)(x + k);
    acc += w4.x * x4.x + w4.y * x4.y + w4.z * x4.z + w4.w * x4.w;
  }
  acc = wave_reduce_sum(acc);
  if (lane == 0) y[w] = acc + b[w];
}

// gate-parallel LSTM: one block (4 waves) per unit j; wave g computes gate g
// (rows g*H+j of Wih and Whh), LDS combine, thread 0 applies activations.
__global__ void lstm_k(const float* __restrict__ Wih, const float* __restrict__ Whh,
                       const float* __restrict__ bih, const float* __restrict__ bhh,
                       const float* __restrict__ x, const float* __restrict__ hin,
                       const float* __restrict__ cin,
                       float* __restrict__ hout, float* __restrict__ cout,
                       float* __restrict__ xnext) {
  int j = blockIdx.x;            // 0..2047
  int g = threadIdx.x >> 6;      // 0..3 (gate = wave index)
  int lane = threadIdx.x & 63;
  const float* wi = Wih + (size_t)(g * H + j) * H;
  const float* wh = Whh + (size_t)(g * H + j) * H;
  float a = 0.f;
  #pragma unroll
  for (int k = lane * 4; k < H; k += 256) {
    float4 wi4 = *(const float4*)(wi + k);
    float4 x4 = *(const float4*)(x + k);
    a += wi4.x * x4.x + wi4.y * x4.y + wi4.z * x4.z + wi4.w * x4.w;
    float4 wh4 = *(const float4*)(wh + k);
    float4 h4 = *(const float4*)(hin + k);
    a += wh4.x * h4.x + wh4.y * h4.y + wh4.z * h4.z + wh4.w * h4.w;
  }
  a = wave_reduce_sum(a);
  __shared__ float gate[4];
  if (lane == 0) gate[g] = a + bih[g * H + j] + bhh[g * H + j];
  __syncthreads();
  if (threadIdx.x == 0) {
    float ig = sigmoidf_(gate[0]);
    float fg = sigmoidf_(gate[1]);
    float gg = tanhf(gate[2]);
    float og = sigmoidf_(gate[3]);
    float c = fg * cin[j] + ig * gg;
    float h = og * tanhf(c);
    hout[j] = h;
    cout[j] = c;
    xnext[j] = h;
  }
}

// stage 1: per-block (256 logits) online max + sum-exp partials
__global__ void lse_part_k(const float* __restrict__ logits,
                           float* __restrict__ partials) {
  int tid = threadIdx.x;
  float v = logits[blockIdx.x * 256 + tid];
  float m = wave_reduce_max(v);
  __shared__ float redm[4], reds[4];
  if ((tid & 63) == 0) redm[tid >> 6] = m;
  __syncthreads();
  float M = fmaxf(fmaxf(redm[0], redm[1]), fmaxf(redm[2], redm[3]));
  float s = wave_reduce_sum(expf(v - M));
  if ((tid & 63) == 0) reds[tid >> 6] = s;
  __syncthreads();
  if (tid == 0) {
    partials[2 * blockIdx.x] = M;
    partials[2 * blockIdx.x + 1] = reds[0] + reds[1] + reds[2] + reds[3];
  }
}

// stage 2: each block combines the 125 partials (wave 0, cheap) then subtracts
__global__ void logsoftmax_out_k(const float* __restrict__ logits,
                                 const float* __restrict__ partials,
                                 float* __restrict__ out) {
  __shared__ float s_lse;
  int tid = threadIdx.x;
  if (tid < 64) {
    float m = -INFINITY;
    for (int p = tid; p < 125; p += 64) m = fmaxf(m, partials[2 * p]);
    m = wave_reduce_max(m);
    m = __shfl(m, 0, 64);
    float s = 0.f;
    for (int p = tid; p < 125; p += 64) s += partials[2 * p + 1] * expf(partials[2 * p] - m);
    s = wave_reduce_sum(s);
    if (tid == 0) s_lse = m + logf(s);
  }
  __syncthreads();
  int i = blockIdx.x * 256 + tid;
  out[i] = logits[i] - s_lse;
}

extern "C" void kernel_launch(void* const* d_in, const int* in_sizes, int n_in,
                              void* d_out, int out_size, void* d_ws, size_t ws_size,
                              hipStream_t stream) {
  const int* idx = (const int*)d_in[0];
  const float* hidden = (const float*)d_in[1];   // [2,1,2048]
  const float* cell = (const float*)d_in[2];     // [2,1,2048]
  const float* enc = (const float*)d_in[3];      // [50,2048]
  const float* embed = (const float*)d_in[4];    // [32000,2048]
  const float* attn_W = (const float*)d_in[5];   // [50,4096]
  const float* attn_b = (const float*)d_in[6];   // [50]
  const float* comb_W = (const float*)d_in[7];   // [2048,4096]
  const float* comb_b = (const float*)d_in[8];   // [2048]
  const float* Wih = (const float*)d_in[9];      // [2,8192,2048]
  const float* Whh = (const float*)d_in[10];     // [2,8192,2048]
  const float* bih = (const float*)d_in[11];     // [2,8192]
  const float* bhh = (const float*)d_in[12];     // [2,8192]
  const float* out_W = (const float*)d_in[13];   // [32000,2048]
  const float* out_b = (const float*)d_in[14];   // [32000]
  float* out = (float*)d_out;

  // workspace layout (floats)
  float* ws = (float*)d_ws;
  float* scores = ws;            // 50 raw scores
  float* partials = ws + 64;     // 250 (125 pairs: max, sumexp)
  float* xcat = ws + 512;        // 4096
  float* x0 = xcat + 4096;       // 2048  (combine output)
  float* x1 = x0 + 2048;         // 2048  (layer0 h)
  float* x2 = x1 + 2048;         // 2048  (layer1 h)
  float* logits = ws + 16384;    // 32000

  // output layout: logits(32000) | h_stack(4096) | c_stack(4096) | attn_weights(50)
  float* out_h = out + 32000;
  float* out_c = out + 36096;
  float* out_attnw = out + 40192;

  attn_scores_k<<<ATTN, 64, 0, stream>>>(idx, embed, hidden, attn_W, attn_b, scores);
  attn_apply_k<<<8, 256, 0, stream>>>(idx, embed, scores, enc, xcat, out_attnw);
  matvec_k<4096><<<512, 256, 0, stream>>>(comb_W, xcat, comb_b, x0, H);
  lstm_k<<<2048, 256, 0, stream>>>(Wih, Whh, bih, bhh, x0, hidden, cell,
                                   out_h, out_c, x1);
  lstm_k<<<2048, 256, 0, stream>>>(Wih + (size_t)4 * H * H, Whh + (size_t)4 * H * H,
                                   bih + 4 * H, bhh + 4 * H,
                                   x1, hidden + H, cell + H,
                                   out_h + H, out_c + H, x2);
  matvec_k<2048><<<8000, 256, 0, stream>>>(out_W, x2, out_b, logits, OUTSZ);
  lse_part_k<<<125, 256, 0, stream>>>(logits, partials);
  logsoftmax_out_k<<<125, 256, 0, stream>>>(logits, partials, out);
}

// Round 4
// 121.752 us; speedup vs baseline: 1.2916x; 1.0669x over previous
//
#include <hip/hip_runtime.h>
#include <math.h>

#define H 2048
#define E 2048
#define ATTN 50
#define OUTSZ 32000

typedef float f32x4 __attribute__((ext_vector_type(4)));

__device__ inline float wave_reduce_sum(float v) {
  #pragma unroll
  for (int off = 32; off > 0; off >>= 1) v += __shfl_down(v, off, 64);
  return v;
}

__device__ inline float wave_reduce_max(float v) {
  #pragma unroll
  for (int off = 32; off > 0; off >>= 1) v = fmaxf(v, __shfl_down(v, off, 64));
  return v;
}

__device__ inline float sigmoidf_(float x) { return 1.f / (1.f + expf(-x)); }

__device__ inline f32x4 nt4(const float* p) {
  return __builtin_nontemporal_load((const f32x4*)p);
}
__device__ inline f32x4 ld4(const float* p) {
  return *(const f32x4*)p;
}
__device__ inline float dot4(f32x4 a, f32x4 b) {
  return a.x * b.x + a.y * b.y + a.z * b.z + a.w * b.w;
}

// K1: fused. Blocks [0,4096): ghh[r] = Whh_row_r · hidden[layer] + bhh[r]  (wave per row, 16384 rows)
//     Blocks [4096,4146): attention scores (block per position, 256 threads over K=4096)
__global__ void k1_ghh_scores(const float* __restrict__ Whh, const float* __restrict__ bhh,
                              const float* __restrict__ hidden,
                              const int* __restrict__ idx, const float* __restrict__ embed_table,
                              const float* __restrict__ attn_W, const float* __restrict__ attn_b,
                              float* __restrict__ ghh, float* __restrict__ scores) {
  int b = blockIdx.x;
  if (b < 4096) {
    int r = b * 4 + (threadIdx.x >> 6);   // global row 0..16383 (layer = r>>13)
    int lane = threadIdx.x & 63;
    int l = r >> 13;
    const float* w = Whh + (size_t)r * H;
    const float* h = hidden + l * H;
    float a = 0.f;
    #pragma unroll
    for (int k = lane * 4; k < H; k += 256) {
      a += dot4(nt4(w + k), ld4(h + k));
    }
    a = wave_reduce_sum(a);
    if (lane == 0) ghh[r] = a + bhh[r];
  } else {
    int t = b - 4096;                      // 0..49
    int tid = threadIdx.x;
    const float* emb = embed_table + (size_t)idx[0] * E;
    const float* row = attn_W + (size_t)t * (E + H);
    float a = 0.f;
    #pragma unroll
    for (int it = 0; it < 4; it++) {
      int k = tid * 4 + it * 1024;
      f32x4 w4 = ld4(row + k);
      const float* src = (k < E) ? (emb + k) : (hidden + (k - E));
      a += dot4(w4, ld4(src));
    }
    a = wave_reduce_sum(a);
    __shared__ float red[4];
    if ((tid & 63) == 0) red[tid >> 6] = a;
    __syncthreads();
    if (tid == 0) scores[t] = red[0] + red[1] + red[2] + red[3] + attn_b[t];
  }
}

// K2: each block recomputes softmax over 50 scores (cheap), writes its slice of
// xcat = [emb, softmax @ enc]. Block 0 writes attn_weights output.
__global__ void attn_apply_k(const int* __restrict__ idx,
                             const float* __restrict__ embed_table,
                             const float* __restrict__ scores,
                             const float* __restrict__ enc,
                             float* __restrict__ xcat,
                             float* __restrict__ attnw_out) {
  __shared__ float w[ATTN];
  int tid = threadIdx.x;
  if (tid < 64) {
    float v = (tid < ATTN) ? scores[tid] : -INFINITY;
    float m = wave_reduce_max(v);
    m = __shfl(m, 0, 64);
    float e = (tid < ATTN) ? expf(v - m) : 0.f;
    float s = wave_reduce_sum(e);
    s = __shfl(s, 0, 64);
    if (tid < ATTN) {
      float ww = e / s;
      w[tid] = ww;
      if (blockIdx.x == 0) attnw_out[tid] = ww;
    }
  }
  __syncthreads();
  int j = blockIdx.x * 256 + tid;
  const float* emb = embed_table + (size_t)idx[0] * E;
  float a = 0.f;
  #pragma unroll 10
  for (int t = 0; t < ATTN; t++) a += w[t] * enc[t * H + j];
  xcat[j] = emb[j];
  xcat[E + j] = a;
}

// K3: comb matvec, block per row (K=4096)
__global__ void comb_k(const float* __restrict__ W, const float* __restrict__ xcat,
                       const float* __restrict__ bias, float* __restrict__ y) {
  int r = blockIdx.x;
  int tid = threadIdx.x;
  const float* row = W + (size_t)r * 4096;
  float a = 0.f;
  #pragma unroll
  for (int it = 0; it < 4; it++) {
    int k = tid * 4 + it * 1024;
    a += dot4(nt4(row + k), ld4(xcat + k));
  }
  a = wave_reduce_sum(a);
  __shared__ float red[4];
  if ((tid & 63) == 0) red[tid >> 6] = a;
  __syncthreads();
  if (tid == 0) y[r] = red[0] + red[1] + red[2] + red[3] + bias[r];
}

// K4/K5: LSTM with precomputed ghh. Block per unit j; wave g computes Wih gate row.
__global__ void lstm_k(const float* __restrict__ Wih, const float* __restrict__ bih,
                       const float* __restrict__ ghh,
                       const float* __restrict__ x, const float* __restrict__ cin,
                       float* __restrict__ hout, float* __restrict__ cout,
                       float* __restrict__ xnext) {
  int j = blockIdx.x;
  int g = threadIdx.x >> 6;
  int lane = threadIdx.x & 63;
  const float* w = Wih + (size_t)(g * H + j) * H;
  float a = 0.f;
  #pragma unroll
  for (int k = lane * 4; k < H; k += 256) {
    a += dot4(nt4(w + k), ld4(x + k));
  }
  a = wave_reduce_sum(a);
  __shared__ float gate[4];
  if (lane == 0) gate[g] = a + bih[g * H + j] + ghh[g * H + j];
  __syncthreads();
  if (threadIdx.x == 0) {
    float ig = sigmoidf_(gate[0]);
    float fg = sigmoidf_(gate[1]);
    float gg = tanhf(gate[2]);
    float og = sigmoidf_(gate[3]);
    float c = fg * cin[j] + ig * gg;
    float h = og * tanhf(c);
    hout[j] = h;
    cout[j] = c;
    xnext[j] = h;
  }
}

// K6: out_W matvec, 2 rows per wave (8 rows/block) + fused per-block LSE partial
__global__ void outw_k(const float* __restrict__ W, const float* __restrict__ x,
                       const float* __restrict__ b,
                       float* __restrict__ logits, float* __restrict__ partials) {
  int wid = threadIdx.x >> 6;
  int lane = threadIdx.x & 63;
  int r0 = blockIdx.x * 8 + wid * 2;
  const float* w0 = W + (size_t)r0 * H;
  const float* w1 = w0 + H;
  float a0 = 0.f, a1 = 0.f;
  #pragma unroll
  for (int k = lane * 4; k < H; k += 256) {
    f32x4 x4 = ld4(x + k);
    a0 += dot4(nt4(w0 + k), x4);
    a1 += dot4(nt4(w1 + k), x4);
  }
  a0 = wave_reduce_sum(a0);
  a1 = wave_reduce_sum(a1);
  __shared__ float lv[8];
  if (lane == 0) {
    float v0 = a0 + b[r0];
    float v1 = a1 + b[r0 + 1];
    logits[r0] = v0;
    logits[r0 + 1] = v1;
    lv[wid * 2] = v0;
    lv[wid * 2 + 1] = v1;
  }
  __syncthreads();
  if (threadIdx.x == 0) {
    float m = -INFINITY;
    #pragma unroll
    for (int i = 0; i < 8; i++) m = fmaxf(m, lv[i]);
    float s = 0.f;
    #pragma unroll
    for (int i = 0; i < 8; i++) s += expf(lv[i] - m);
    partials[2 * blockIdx.x] = m;
    partials[2 * blockIdx.x + 1] = s;
  }
}

// K7: combine 4000 partials (wave 0) then subtract
__global__ void lsm_out_k(const float* __restrict__ logits,
                          const float* __restrict__ partials,
                          float* __restrict__ out) {
  __shared__ float s_lse;
  int tid = threadIdx.x;
  if (tid < 64) {
    float m = -INFINITY;
    for (int p = tid; p < 4000; p += 64) m = fmaxf(m, partials[2 * p]);
    m = wave_reduce_max(m);
    m = __shfl(m, 0, 64);
    float s = 0.f;
    for (int p = tid; p < 4000; p += 64) s += partials[2 * p + 1] * expf(partials[2 * p] - m);
    s = wave_reduce_sum(s);
    if (tid == 0) s_lse = m + logf(s);
  }
  __syncthreads();
  int i = blockIdx.x * 256 + tid;
  out[i] = logits[i] - s_lse;
}

extern "C" void kernel_launch(void* const* d_in, const int* in_sizes, int n_in,
                              void* d_out, int out_size, void* d_ws, size_t ws_size,
                              hipStream_t stream) {
  const int* idx = (const int*)d_in[0];
  const float* hidden = (const float*)d_in[1];   // [2,1,2048]
  const float* cell = (const float*)d_in[2];     // [2,1,2048]
  const float* enc = (const float*)d_in[3];      // [50,2048]
  const float* embed = (const float*)d_in[4];    // [32000,2048]
  const float* attn_W = (const float*)d_in[5];   // [50,4096]
  const float* attn_b = (const float*)d_in[6];   // [50]
  const float* comb_W = (const float*)d_in[7];   // [2048,4096]
  const float* comb_b = (const float*)d_in[8];   // [2048]
  const float* Wih = (const float*)d_in[9];      // [2,8192,2048]
  const float* Whh = (const float*)d_in[10];     // [2,8192,2048]
  const float* bih = (const float*)d_in[11];     // [2,8192]
  const float* bhh = (const float*)d_in[12];     // [2,8192]
  const float* out_W = (const float*)d_in[13];   // [32000,2048]
  const float* out_b = (const float*)d_in[14];   // [32000]
  float* out = (float*)d_out;

  // workspace layout (floats)
  float* ws = (float*)d_ws;
  float* scores = ws;             // 50
  float* xcat = ws + 64;          // 4096
  float* x0 = xcat + 4096;        // 2048
  float* x1 = x0 + 2048;          // 2048
  float* x2 = x1 + 2048;          // 2048
  float* ghh = ws + 12288;        // 16384 ([2][8192], bhh included)
  float* logits = ws + 32768;     // 32000
  float* partials = ws + 65536;   // 8000 (4000 pairs)

  // output layout: logits(32000) | h_stack(4096) | c_stack(4096) | attn_weights(50)
  float* out_h = out + 32000;
  float* out_c = out + 36096;
  float* out_attnw = out + 40192;

  k1_ghh_scores<<<4146, 256, 0, stream>>>(Whh, bhh, hidden, idx, embed,
                                          attn_W, attn_b, ghh, scores);
  attn_apply_k<<<8, 256, 0, stream>>>(idx, embed, scores, enc, xcat, out_attnw);
  comb_k<<<2048, 256, 0, stream>>>(comb_W, xcat, comb_b, x0);
  lstm_k<<<2048, 256, 0, stream>>>(Wih, bih, ghh, x0, cell, out_h, out_c, x1);
  lstm_k<<<2048, 256, 0, stream>>>(Wih + (size_t)4 * H * H, bih + 4 * H, ghh + 4 * H,
                                   x1, cell + H, out_h + H, out_c + H, x2);
  outw_k<<<4000, 256, 0, stream>>>(out_W, x2, out_b, logits, partials);
  lsm_out_k<<<125, 256, 0, stream>>>(logits, partials, out);
}